// Round 1
// baseline (252.466 us; speedup 1.0000x reference)
//
#include <hip/hip_runtime.h>
#include <math.h>

// Problem shapes (fixed by setup_inputs)
#define BB   16
#define AA   3
#define HHH  80
#define WWW  80
#define CHN  85
#define TCH  10
#define SEGC 21
#define SH   160
#define SW   160
#define PTOT (BB*AA*HHH*WWW)      // 307200
#define SPIX (BB*SH*SW)           // 409600

__constant__ float c_anchors[3][3][2] = {
  {{10.f,13.f},{16.f,30.f},{33.f,23.f}},
  {{30.f,61.f},{62.f,45.f},{59.f,119.f}},
  {{116.f,90.f},{156.f,198.f},{373.f,326.f}}
};
__constant__ float c_len[3] = {8.f, 16.f, 32.f};

// acc layout (doubles): 0=lbox_sum 1=lobj_sum 2=lcls_sum 3=obj_softplus_sum
//                       4=all_softplus_sum 5=seg_sum

__device__ inline float softplusf(float x) {
  return fmaxf(x, 0.f) + log1pf(expf(-fabsf(x)));
}

__device__ inline void block_reduce_atomic(double v, double* target) {
  #pragma unroll
  for (int off = 32; off; off >>= 1) v += __shfl_xor(v, off, 64);
  __shared__ double sm[8];
  int lane = threadIdx.x & 63, wid = threadIdx.x >> 6;
  if (lane == 0) sm[wid] = v;
  __syncthreads();
  if (threadIdx.x == 0) {
    double r = sm[0];
    int nw = blockDim.x >> 6;
    for (int i = 1; i < nw; ++i) r += sm[i];
    atomicAdd(target, r);
  }
}

// Sum of softplus(obj_logit) over ALL positions (obj positions subtracted in k_obj)
__global__ void k_noobj(const float* __restrict__ prd, double* __restrict__ acc) {
  int idx = blockIdx.x * blockDim.x + threadIdx.x;
  float v = 0.f;
  if (idx < PTOT) {
    float x = prd[(size_t)idx * CHN + 4];
    v = softplusf(x);
  }
  block_reduce_atomic((double)v, &acc[4]);
}

// Seg cross-entropy: one thread per pixel, loop over 21 channel planes
__global__ void k_seg(const float* __restrict__ seg, const int* __restrict__ lab,
                      double* __restrict__ acc) {
  int pix = blockIdx.x * blockDim.x + threadIdx.x;
  float loss = 0.f;
  if (pix < SPIX) {
    int b = pix / (SH*SW);
    int r = pix - b * (SH*SW);
    const float* p = seg + (size_t)b * SEGC * SH * SW + r;
    int L = lab[pix];
    float vals[SEGC];
    float m = -INFINITY;
    #pragma unroll
    for (int c = 0; c < SEGC; ++c) {
      vals[c] = p[(size_t)c * SH * SW];
      m = fmaxf(m, vals[c]);
    }
    float s = 0.f, sl = 0.f;
    #pragma unroll
    for (int c = 0; c < SEGC; ++c) {
      s += expf(vals[c] - m);
      if (c == L) sl = vals[c];
    }
    loss = m + logf(s) - sl;   // -log_softmax at label
  }
  block_reduce_atomic((double)loss, &acc[5]);
}

// One wave per object: box CIoU + obj BCE + cls CE + softplus correction
__global__ void __launch_bounds__(64) k_obj(const float* __restrict__ prd,
                                            const float* __restrict__ tgt,
                                            const int* __restrict__ ind,
                                            const int* __restrict__ fidx,
                                            double* __restrict__ acc, int N) {
  const int t = threadIdx.x;
  const int f = fidx[0];
  const float lw = c_len[f], lh = c_len[f];
  const float eps = 1e-7f;
  double lbox = 0, lobj = 0, lcls = 0, osp = 0;

  for (int obj = blockIdx.x; obj < N; obj += gridDim.x) {
    int b  = ind[obj];
    int a  = ind[N + obj];
    int hh = ind[2*N + obj];
    int ww = ind[3*N + obj];
    size_t cell  = (((size_t)b*AA + a)*HHH + hh)*WWW + ww;
    size_t pbase = cell * CHN;
    size_t tbase = cell * TCH;

    float v0 = prd[pbase + t];                        // ps[0..63]
    float v1 = (t < CHN - 64) ? prd[pbase + 64 + t] : 0.f;  // ps[64..84]

    // logsumexp over classes 5..84
    float a0 = (t >= 5) ? v0 : -INFINITY;
    float a1 = (t < CHN - 64) ? v1 : -INFINITY;
    float m = fmaxf(a0, a1);
    #pragma unroll
    for (int off = 32; off; off >>= 1) m = fmaxf(m, __shfl_xor(m, off, 64));
    float s = ((t >= 5) ? expf(a0 - m) : 0.f) + ((t < CHN - 64) ? expf(a1 - m) : 0.f);
    #pragma unroll
    for (int off = 32; off; off >>= 1) s += __shfl_xor(s, off, 64);
    float lse = m + logf(s);

    float ps0 = __shfl(v0, 0, 64), ps1 = __shfl(v0, 1, 64), ps2 = __shfl(v0, 2, 64),
          ps3 = __shfl(v0, 3, 64), ps4 = __shfl(v0, 4, 64);

    float ts0 = tgt[tbase+1], ts1 = tgt[tbase+2], ts2 = tgt[tbase+3], ts3 = tgt[tbase+4];
    int lab = (int)tgt[tbase+9];
    int ci = 5 + lab;
    float psl = (ci < 64) ? __shfl(v0, ci, 64) : __shfl(v1, ci - 64, 64);

    // predicted box
    float sx = 1.f/(1.f + expf(-ps0)), sy = 1.f/(1.f + expf(-ps1));
    float px = lw*(sx + (float)ww), py = lh*(sy + (float)hh);
    float pcw = c_anchors[f][a][0]*expf(ps2);
    float pch = c_anchors[f][a][1]*expf(ps3);

    // ciou_xywh(pbox, ts)
    float b1x1 = px - pcw*0.5f, b1x2 = px + pcw*0.5f;
    float b1y1 = py - pch*0.5f, b1y2 = py + pch*0.5f;
    float b2x1 = ts0 - ts2*0.5f, b2x2 = ts0 + ts2*0.5f;
    float b2y1 = ts1 - ts3*0.5f, b2y2 = ts1 + ts3*0.5f;
    float iw = fminf(b1x2,b2x2) - fmaxf(b1x1,b2x1);
    float ih = fminf(b1y2,b2y2) - fmaxf(b1y1,b2y1);
    float inter = fmaxf(iw,0.f)*fmaxf(ih,0.f);
    float w1 = b1x2-b1x1, h1 = b1y2-b1y1+eps;
    float w2 = b2x2-b2x1, h2 = b2y2-b2y1+eps;
    float uni = w1*h1 + w2*h2 - inter + eps;
    float iou = inter/uni;
    float cwv = fmaxf(b1x2,b2x2) - fminf(b1x1,b2x1);
    float chv = fmaxf(b1y2,b2y2) - fminf(b1y1,b2y1);
    float c2 = cwv*cwv + chv*chv + eps;
    float dxv = b2x1+b2x2-b1x1-b1x2, dyv = b2y1+b2y2-b1y1-b1y2;
    float rho2 = (dxv*dxv + dyv*dyv)*0.25f;
    float da = atanf(w2/h2) - atanf(w1/h1);
    float vterm = (4.f/(float)(M_PI*M_PI)) * da * da;
    float alpha = vterm/(vterm - iou + 1.f + eps);
    float ciou = iou - (rho2/c2 + vterm*alpha);
    lbox += (double)(1.f - ciou);

    // one_iou: pxyxy vs ts treated as xyxy
    float ix1 = fmaxf(b1x1, ts0), iy1 = fmaxf(b1y1, ts1);
    float ix2 = fminf(b1x2, ts2), iy2 = fminf(b1y2, ts3);
    float inter2 = fmaxf(ix2-ix1,0.f)*fmaxf(iy2-iy1,0.f);
    float a1r = (b1x2-b1x1)*(b1y2-b1y1);
    float a2r = (ts2-ts0)*(ts3-ts1);
    float one_iou = inter2/(a1r + a2r - inter2);

    // bce_logits(ps4, one_iou)
    lobj += (double)(fmaxf(ps4,0.f) - ps4*one_iou + log1pf(expf(-fabsf(ps4))));
    // cls CE
    lcls += (double)(lse - psl);
    // softplus correction for noobj
    osp  += (double)softplusf(ps4);
  }

  if (t == 0) {
    atomicAdd(&acc[0], lbox);
    atomicAdd(&acc[1], lobj);
    atomicAdd(&acc[2], lcls);
    atomicAdd(&acc[3], osp);
  }
}

__global__ void k_final(const double* __restrict__ acc, float* __restrict__ out, int N) {
  double lbox = acc[0] / N;
  double lobj = acc[1] / N;
  double lcls = acc[2] / N;
  double lnoobj = (acc[4] - acc[3]) / (double)(PTOT - N);
  double lseg = acc[5] / (double)SPIX;
  out[0] = (float)(3.0*lbox + 1.0*lobj + 10.0*lnoobj + lcls + 2.0*lseg);
}

extern "C" void kernel_launch(void* const* d_in, const int* in_sizes, int n_in,
                              void* d_out, int out_size, void* d_ws, size_t ws_size,
                              hipStream_t stream) {
  const float* prd  = (const float*)d_in[0];
  const float* tgt  = (const float*)d_in[1];
  const int*   ind  = (const int*)d_in[2];
  const int*   fidx = (const int*)d_in[3];
  const float* seg  = (const float*)d_in[4];
  const int*   slab = (const int*)d_in[5];
  float* out = (float*)d_out;
  double* acc = (double*)d_ws;
  int N = in_sizes[2] / 4;   // indices_f is (4, N)

  hipMemsetAsync(d_ws, 0, 6*sizeof(double), stream);
  k_noobj<<<(PTOT + 255)/256, 256, 0, stream>>>(prd, acc);
  k_obj  <<<512, 64, 0, stream>>>(prd, tgt, ind, fidx, acc, N);
  k_seg  <<<(SPIX + 255)/256, 256, 0, stream>>>(seg, slab, acc);
  k_final<<<1, 1, 0, stream>>>(acc, out, N);
}

// Round 2
// 235.687 us; speedup vs baseline: 1.0712x; 1.0712x over previous
//
#include <hip/hip_runtime.h>
#include <math.h>

// Problem shapes (fixed by setup_inputs)
#define BB   16
#define AA   3
#define HHH  80
#define WWW  80
#define CHN  85
#define TCH  10
#define SEGC 21
#define SH   160
#define SW   160
#define PTOT (BB*AA*HHH*WWW)      // 307200
#define SPIX (BB*SH*SW)           // 409600
#define PIX_PER_IMG (SH*SW)       // 25600
#define F4_PER_IMG (PIX_PER_IMG/4) // 6400

// Block sections of the fused kernel
#define NB_NOOBJ 300   // 300 blocks * 256 thr * 4 cells  = 307200
#define NB_SEG   400   // 400 blocks * 256 thr * 4 pixels = 409600
#define NB_OBJ   512   // 512 blocks * 4 waves, grid-stride over 4096 objs
#define NB_TOTAL (NB_NOOBJ + NB_SEG + NB_OBJ)

__constant__ float c_anchors[3][3][2] = {
  {{10.f,13.f},{16.f,30.f},{33.f,23.f}},
  {{30.f,61.f},{62.f,45.f},{59.f,119.f}},
  {{116.f,90.f},{156.f,198.f},{373.f,326.f}}
};
__constant__ float c_len[3] = {8.f, 16.f, 32.f};

// acc layout (doubles): 0=lbox 1=lobj 2=lcls 3=obj_softplus 4=all_softplus
//                       5=seg_sum 6=(unused) 7=done counter (as uint)

__device__ inline float softplusf(float x) {
  return fmaxf(x, 0.f) + log1pf(expf(-fabsf(x)));
}

// 256-thread block: wave shuffle reduce -> shared -> one f64 atomic
__device__ inline void block_reduce_atomic(double v, double* target) {
  #pragma unroll
  for (int off = 32; off; off >>= 1) v += __shfl_xor(v, off, 64);
  __shared__ double sm[4];
  int lane = threadIdx.x & 63, wid = threadIdx.x >> 6;
  if (lane == 0) sm[wid] = v;
  __syncthreads();
  if (threadIdx.x == 0) {
    atomicAdd(target, sm[0] + sm[1] + sm[2] + sm[3]);
  }
}

__global__ void __launch_bounds__(256) k_fused(
    const float* __restrict__ prd, const float* __restrict__ tgt,
    const int* __restrict__ ind, const int* __restrict__ fidx,
    const float* __restrict__ seg, const int* __restrict__ lab,
    double* __restrict__ acc, float* __restrict__ out, int N) {
  const int t = threadIdx.x;
  const int blk = blockIdx.x;

  if (blk < NB_NOOBJ) {
    // ---- Section A: softplus(obj_logit) over ALL cells ----
    int base = blk * 1024 + t;
    float s = 0.f;
    #pragma unroll
    for (int k = 0; k < 4; ++k) {
      float x = prd[(size_t)(base + k * 256) * CHN + 4];
      s += softplusf(x);
    }
    block_reduce_atomic((double)s, &acc[4]);
  } else if (blk < NB_NOOBJ + NB_SEG) {
    // ---- Section B: seg cross-entropy, float4 x 4 pixels/thread ----
    int g4 = (blk - NB_NOOBJ) * 256 + t;           // float4 index, 0..102399
    int bimg = g4 / F4_PER_IMG;
    int r4 = g4 - bimg * F4_PER_IMG;
    const float4* sp = (const float4*)(seg + (size_t)bimg * SEGC * PIX_PER_IMG) + r4;
    int4 L = ((const int4*)lab)[g4];
    float vx[SEGC], vy[SEGC], vz[SEGC], vw[SEGC];
    float mx = -INFINITY, my = -INFINITY, mz = -INFINITY, mw = -INFINITY;
    #pragma unroll
    for (int c = 0; c < SEGC; ++c) {
      float4 v = sp[(size_t)c * F4_PER_IMG];
      vx[c] = v.x; vy[c] = v.y; vz[c] = v.z; vw[c] = v.w;
      mx = fmaxf(mx, v.x); my = fmaxf(my, v.y);
      mz = fmaxf(mz, v.z); mw = fmaxf(mw, v.w);
    }
    float sx = 0.f, sy = 0.f, sz = 0.f, sw = 0.f;
    float lx = 0.f, ly = 0.f, lz = 0.f, lwv = 0.f;
    #pragma unroll
    for (int c = 0; c < SEGC; ++c) {
      sx += expf(vx[c] - mx); sy += expf(vy[c] - my);
      sz += expf(vz[c] - mz); sw += expf(vw[c] - mw);
      if (c == L.x) lx = vx[c];
      if (c == L.y) ly = vy[c];
      if (c == L.z) lz = vz[c];
      if (c == L.w) lwv = vw[c];
    }
    float loss = (mx + logf(sx) - lx) + (my + logf(sy) - ly)
               + (mz + logf(sz) - lz) + (mw + logf(sw) - lwv);
    block_reduce_atomic((double)loss, &acc[5]);
  } else {
    // ---- Section C: wave-per-object box/obj/cls ----
    const int bc = blk - NB_NOOBJ - NB_SEG;
    const int wv = t >> 6, ln = t & 63;
    const int f = fidx[0];
    const float lw = c_len[f], lh = c_len[f];
    const float eps = 1e-7f;
    double lbox = 0, lobj = 0, lcls = 0, osp = 0;

    for (int obj = bc * 4 + wv; obj < N; obj += NB_OBJ * 4) {
      int b  = ind[obj];
      int a  = ind[N + obj];
      int hh = ind[2*N + obj];
      int ww = ind[3*N + obj];
      size_t cell  = (((size_t)b*AA + a)*HHH + hh)*WWW + ww;
      size_t pbase = cell * CHN;
      size_t tbase = cell * TCH;

      float v0 = prd[pbase + ln];
      float v1 = (ln < CHN - 64) ? prd[pbase + 64 + ln] : 0.f;

      // logsumexp over classes 5..84
      float a0 = (ln >= 5) ? v0 : -INFINITY;
      float a1 = (ln < CHN - 64) ? v1 : -INFINITY;
      float m = fmaxf(a0, a1);
      #pragma unroll
      for (int off = 32; off; off >>= 1) m = fmaxf(m, __shfl_xor(m, off, 64));
      float s = ((ln >= 5) ? expf(a0 - m) : 0.f) + ((ln < CHN - 64) ? expf(a1 - m) : 0.f);
      #pragma unroll
      for (int off = 32; off; off >>= 1) s += __shfl_xor(s, off, 64);
      float lse = m + logf(s);

      float ps0 = __shfl(v0, 0, 64), ps1 = __shfl(v0, 1, 64), ps2 = __shfl(v0, 2, 64),
            ps3 = __shfl(v0, 3, 64), ps4 = __shfl(v0, 4, 64);

      float ts0 = tgt[tbase+1], ts1 = tgt[tbase+2], ts2 = tgt[tbase+3], ts3 = tgt[tbase+4];
      int lab2 = (int)tgt[tbase+9];
      int ci = 5 + lab2;
      float psl = (ci < 64) ? __shfl(v0, ci, 64) : __shfl(v1, ci - 64, 64);

      float sxg = 1.f/(1.f + expf(-ps0)), syg = 1.f/(1.f + expf(-ps1));
      float px = lw*(sxg + (float)ww), py = lh*(syg + (float)hh);
      float pcw = c_anchors[f][a][0]*expf(ps2);
      float pch = c_anchors[f][a][1]*expf(ps3);

      float b1x1 = px - pcw*0.5f, b1x2 = px + pcw*0.5f;
      float b1y1 = py - pch*0.5f, b1y2 = py + pch*0.5f;
      float b2x1 = ts0 - ts2*0.5f, b2x2 = ts0 + ts2*0.5f;
      float b2y1 = ts1 - ts3*0.5f, b2y2 = ts1 + ts3*0.5f;
      float iw = fminf(b1x2,b2x2) - fmaxf(b1x1,b2x1);
      float ih = fminf(b1y2,b2y2) - fmaxf(b1y1,b2y1);
      float inter = fmaxf(iw,0.f)*fmaxf(ih,0.f);
      float w1 = b1x2-b1x1, h1 = b1y2-b1y1+eps;
      float w2 = b2x2-b2x1, h2 = b2y2-b2y1+eps;
      float uni = w1*h1 + w2*h2 - inter + eps;
      float iou = inter/uni;
      float cwv = fmaxf(b1x2,b2x2) - fminf(b1x1,b2x1);
      float chv = fmaxf(b1y2,b2y2) - fminf(b1y1,b2y1);
      float c2 = cwv*cwv + chv*chv + eps;
      float dxv = b2x1+b2x2-b1x1-b1x2, dyv = b2y1+b2y2-b1y1-b1y2;
      float rho2 = (dxv*dxv + dyv*dyv)*0.25f;
      float da = atanf(w2/h2) - atanf(w1/h1);
      float vterm = (4.f/(float)(M_PI*M_PI)) * da * da;
      float alpha = vterm/(vterm - iou + 1.f + eps);
      float ciou = iou - (rho2/c2 + vterm*alpha);
      lbox += (double)(1.f - ciou);

      float ix1 = fmaxf(b1x1, ts0), iy1 = fmaxf(b1y1, ts1);
      float ix2 = fminf(b1x2, ts2), iy2 = fminf(b1y2, ts3);
      float inter2 = fmaxf(ix2-ix1,0.f)*fmaxf(iy2-iy1,0.f);
      float a1r = (b1x2-b1x1)*(b1y2-b1y1);
      float a2r = (ts2-ts0)*(ts3-ts1);
      float one_iou = inter2/(a1r + a2r - inter2);

      lobj += (double)(fmaxf(ps4,0.f) - ps4*one_iou + log1pf(expf(-fabsf(ps4))));
      lcls += (double)(lse - psl);
      osp  += (double)softplusf(ps4);
    }

    __shared__ double ssum[4][4];
    if (ln == 0) {
      ssum[wv][0] = lbox; ssum[wv][1] = lobj; ssum[wv][2] = lcls; ssum[wv][3] = osp;
    }
    __syncthreads();
    if (t == 0) {
      #pragma unroll
      for (int j = 0; j < 4; ++j) {
        atomicAdd(&acc[j], ssum[0][j] + ssum[1][j] + ssum[2][j] + ssum[3][j]);
      }
    }
  }

  // ---- done-counter finalize (last block computes the scalar) ----
  if (t == 0) {
    __threadfence();
    unsigned* cnt = (unsigned*)(acc + 7);
    unsigned old = atomicAdd(cnt, 1u);
    if (old == (unsigned)(NB_TOTAL - 1)) {
      // atomic reads for cross-XCD coherence
      double albox = atomicAdd(&acc[0], 0.0);
      double alobj = atomicAdd(&acc[1], 0.0);
      double alcls = atomicAdd(&acc[2], 0.0);
      double aosp  = atomicAdd(&acc[3], 0.0);
      double aall  = atomicAdd(&acc[4], 0.0);
      double aseg  = atomicAdd(&acc[5], 0.0);
      double lnoobj = (aall - aosp) / (double)(PTOT - N);
      out[0] = (float)(3.0*(albox/N) + (alobj/N) + 10.0*lnoobj + (alcls/N)
                       + 2.0*(aseg/(double)SPIX));
    }
  }
}

extern "C" void kernel_launch(void* const* d_in, const int* in_sizes, int n_in,
                              void* d_out, int out_size, void* d_ws, size_t ws_size,
                              hipStream_t stream) {
  const float* prd  = (const float*)d_in[0];
  const float* tgt  = (const float*)d_in[1];
  const int*   ind  = (const int*)d_in[2];
  const int*   fidx = (const int*)d_in[3];
  const float* seg  = (const float*)d_in[4];
  const int*   slab = (const int*)d_in[5];
  float* out = (float*)d_out;
  double* acc = (double*)d_ws;
  int N = in_sizes[2] / 4;   // indices_f is (4, N)

  hipMemsetAsync(d_ws, 0, 8*sizeof(double), stream);
  k_fused<<<NB_TOTAL, 256, 0, stream>>>(prd, tgt, ind, fidx, seg, slab, acc, out, N);
}